// Round 5
// baseline (3827.481 us; speedup 1.0000x reference)
//
#include <hip/hip_runtime.h>
#include <cstdint>
#include <cmath>

#define S_LEN 1024
#define BATCH 64
#define IN_SZ 256
#define HID 512
#define OUT_SZ 256
#define WIH_LD 768  // W_ih leading dim = IN_SZ + HID
#define BH (BATCH * HID)            // 32768
#define XP_FLOATS (S_LEN * BH)      // 33,554,432 floats (128 MB)

// R5 recurrence structure: 256 threads/WG (4 waves, 1 wave/SIMD), each thread
// owns TWO adjacent outputs j0=2t, j1=2t+1.
// Rationale (R2-R4 counter fits): the critical per-step term was the 512
// broadcast ds_read_b128 hq reads per CU (8 waves x 64 @ ~4cyc ~= 2050cyc)
// -- every wave redundantly broadcasts the same 1KB h-state. Halving the
// wave count (and doubling j per thread) halves the broadcast term while
// keeping total VALU MACs constant. 1 wave/SIMD doubles the unified register
// budget to 512/thread, which holds 2x weights.
//
// Weight pair-index space p in [0,256) per output row j:
//   p in [0,136)    -> register-resident (272 words/thread for 2 j's)
//   p in [136,192)  -> LDS, [g2][t][4] uint4 tiles (2 pairs x 2 j per b128),
//                      lane-stride 16B = conflict-free
//   p in [192,256)  -> streamed/step from L2, 32 uint4/thread, single
//                      upfront batch (R1 lesson: never split mid-chain)
#define P_REG 136
#define P_LDS 56     // 56*512 words = 114,688 B LDS (+1KB h2u x2 = 116,736)
#define P_STR 64     // 16 uint4 groups per j

// ws word layout after xp (wbase = ws + XP_FLOATS):
//  [0, 32768)          wstr2     (64*512 words; rnn streams per step)
//  [32768, 102400)     wregbuf2  (136*512 words as [p][t]{j0,j1})
//  [102400, 131072)    wldsbuf2  (56*512 words, LDS image)
//  [131072, 196608)    wpk       (xproj B-fragments, 16384 uint4 = 256 KB)
//  overlays (used only after rnn completes):
//  [0, 65536)          sc_g[64][1024]
//  [65536, 98304)      ctx_g[64][512]

typedef _Float16 h2v __attribute__((ext_vector_type(2)));
typedef _Float16 f16x8 __attribute__((ext_vector_type(8)));
typedef float f32x4 __attribute__((ext_vector_type(4)));

__device__ __forceinline__ float dot2p(unsigned int a, unsigned int b, float c) {
#if __has_builtin(__builtin_amdgcn_fdot2)
    return __builtin_amdgcn_fdot2(__builtin_bit_cast(h2v, a),
                                  __builtin_bit_cast(h2v, b), c, false);
#else
    h2v av = __builtin_bit_cast(h2v, a);
    h2v bv = __builtin_bit_cast(h2v, b);
    return c + (float)av.x * (float)bv.x + (float)av.y * (float)bv.y;
#endif
}

// Branch-free tanh: 1 - 2/(e^{2x}+1). ~1e-6 abs err, exact limits. (R2 win.)
__device__ __forceinline__ float fast_tanh(float x) {
    float e = __expf(2.0f * x);
#if __has_builtin(__builtin_amdgcn_rcpf)
    float r = __builtin_amdgcn_rcpf(e + 1.0f);
#else
    float r = 1.0f / (e + 1.0f);
#endif
    return __builtin_fmaf(-2.0f, r, 1.0f);
}

__global__ __launch_bounds__(256) void pack_w(const float* __restrict__ W_ih,
                                              unsigned int* __restrict__ wstr2,
                                              unsigned int* __restrict__ wregbuf2,
                                              unsigned int* __restrict__ wldsbuf2) {
    int idx = blockIdx.x * 256 + threadIdx.x;   // 0..131071
    int p = idx & 255;
    int j = idx >> 8;
    const float* src = W_ih + (size_t)j * WIH_LD + IN_SZ + 2 * p;
    unsigned short lo = __builtin_bit_cast(unsigned short, (_Float16)src[0]);
    unsigned short hi = __builtin_bit_cast(unsigned short, (_Float16)src[1]);
    unsigned int u = (unsigned int)lo | ((unsigned int)hi << 16);
    int t = j >> 1;       // owning thread
    int jj = j & 1;       // which of the thread's two outputs
    if (p < P_REG) {
        wregbuf2[(p * 256 + t) * 2 + jj] = u;
    } else if (p < P_REG + P_LDS) {
        int d  = p - P_REG;
        int g2 = d >> 1;      // 0..27
        int e  = d & 1;
        wldsbuf2[(g2 * 256 + t) * 4 + jj * 2 + e] = u;
    } else {
        int q = p - (P_REG + P_LDS);   // 0..63
        int g = q >> 2;                 // 0..15
        int c = q & 3;
        wstr2[((g * 2 + jj) * 256 + t) * 4 + c] = u;
    }
}

// Pack Wx (W_ih[:, 0:256]) into MFMA B-fragment layout, f16.
__global__ __launch_bounds__(256) void pack_wf16(const float* __restrict__ W_ih,
                                                 uint4* __restrict__ wpk) {
    int idx = blockIdx.x * 256 + threadIdx.x;   // 0..16383
    if (idx >= 16384) return;
    int nt   = idx >> 9;
    int ks   = (idx >> 6) & 7;
    int lane = idx & 63;
    int n  = nt * 16 + (lane & 15);
    int kb = ks * 32 + (lane >> 4) * 8;
    const float* src = W_ih + (size_t)n * WIH_LD + kb;
    union { uint4 u; _Float16 h[8]; } v;
#pragma unroll
    for (int i = 0; i < 8; ++i) v.h[i] = (_Float16)src[i];
    wpk[idx] = v.u;
}

// xp[s][b][h] = dot(x[b][s][:], Wx[h][:]) + b_ih[h], via f16 MFMA (fp32 accum).
#define AH_LD 264   // 256 + 8-half pad
__global__ __launch_bounds__(256) void xproj_mfma(const float* __restrict__ x,
                                                  const uint4* __restrict__ wpk,
                                                  const float* __restrict__ b_ih,
                                                  float* __restrict__ xp) {
    const int s    = blockIdx.x;
    const int half = blockIdx.y;
    const int tid  = threadIdx.x;
    __shared__ __align__(16) _Float16 Ah[32 * AH_LD];
    __shared__ float bsh[HID];
    bsh[tid] = b_ih[tid];
    bsh[tid + 256] = b_ih[tid + 256];
    {
        int r  = tid >> 3;
        int c0 = (tid & 7) * 32;
        const float4* s4 = (const float4*)(x + ((size_t)(half * 32 + r) * S_LEN + s) * IN_SZ + c0);
        _Float16* dst = &Ah[r * AH_LD + c0];
#pragma unroll
        for (int i = 0; i < 8; ++i) {
            float4 v = s4[i];
            dst[4 * i + 0] = (_Float16)v.x;
            dst[4 * i + 1] = (_Float16)v.y;
            dst[4 * i + 2] = (_Float16)v.z;
            dst[4 * i + 3] = (_Float16)v.w;
        }
    }
    __syncthreads();
    const int lane = tid & 63;
    const int w    = tid >> 6;
    const int mt   = w & 1;
    const int ntb  = (w >> 1) * 16;
    f16x8 areg[8];
#pragma unroll
    for (int ks = 0; ks < 8; ++ks)
        areg[ks] = *(const f16x8*)&Ah[(mt * 16 + (lane & 15)) * AH_LD + ks * 32 + (lane >> 4) * 8];
    const int brow  = half * 32 + mt * 16 + (lane >> 4) * 4;
    const int ncol0 = lane & 15;
    for (int nt2 = 0; nt2 < 16; ++nt2) {
        int nt = ntb + nt2;
        const uint4* bp = wpk + (size_t)nt * 8 * 64 + lane;
        f32x4 acc = {0.f, 0.f, 0.f, 0.f};
#pragma unroll
        for (int ks = 0; ks < 8; ++ks) {
            uint4 bu = bp[ks * 64];
            acc = __builtin_amdgcn_mfma_f32_16x16x32_f16(
                areg[ks], __builtin_bit_cast(f16x8, bu), acc, 0, 0, 0);
        }
        int n = nt * 16 + ncol0;
        float bias = bsh[n];
        float* outp = xp + (size_t)s * BH + (size_t)brow * HID + n;
#pragma unroll
        for (int r = 0; r < 4; ++r) outp[(size_t)r * HID] = acc[r] + bias;
    }
}

// Recurrence: one WG (256 thr, 4 waves, 1/SIMD) per batch; 2 outputs/thread.
__global__ __launch_bounds__(256, 1) void rnn_f16(const unsigned int* __restrict__ wregbuf2,
                                                  const uint4* __restrict__ wldsbuf2,
                                                  const uint4* __restrict__ wstr2,
                                                  float* __restrict__ xp) {
    const int b = blockIdx.x;
    const int t = threadIdx.x;            // 0..255; j0=2t, j1=2t+1

    __shared__ __align__(16) uint4 wlds[P_LDS / 2 * 256];     // 28*256 uint4 = 114,688 B
    __shared__ __align__(16) unsigned int h2u[2][256];        // 2 KB, 2 packed f16 per word

    // Register-resident weights for both outputs.
    unsigned int wregA[P_REG], wregB[P_REG];
    {
        const uint2* wr2 = (const uint2*)wregbuf2;
#pragma unroll
        for (int p = 0; p < P_REG; ++p) {
            uint2 v = wr2[p * 256 + t];
            wregA[p] = v.x;
            wregB[p] = v.y;
        }
    }
    // Stage LDS weight image (linear copy, both layouts identical).
    for (int i = t; i < P_LDS / 2 * 256; i += 256) wlds[i] = wldsbuf2[i];
    h2u[0][t] = 0;   // two f16 +0.0
    __syncthreads();

    float* col = xp + (size_t)b * HID + 2 * t;
    for (int s = 0; s < S_LEN; ++s) {
        const uint4* hq4 = (const uint4*)&h2u[s & 1][0];   // 64 groups of 4 pairs
        float2 xpv = *(const float2*)(col + (size_t)s * BH);

        // Streamed weights: single upfront batch (32 x dwordx4, L2-resident).
        uint4 swA[16], swB[16];
#pragma unroll
        for (int g = 0; g < 16; ++g) {
            swA[g] = wstr2[g * 512 + t];
            swB[g] = wstr2[g * 512 + 256 + t];
        }

        float aA0 = 0.f, aA1 = 0.f, aA2 = 0.f, aA3 = 0.f;
        float aB0 = 0.f, aB1 = 0.f, aB2 = 0.f, aB3 = 0.f;

        // Register section: pairs [0,136), hq groups [0,34).
#pragma unroll
        for (int g = 0; g < P_REG / 4; ++g) {
            uint4 hh = hq4[g];
            aA0 = dot2p(wregA[4 * g + 0], hh.x, aA0);
            aA1 = dot2p(wregA[4 * g + 1], hh.y, aA1);
            aA2 = dot2p(wregA[4 * g + 2], hh.z, aA2);
            aA3 = dot2p(wregA[4 * g + 3], hh.w, aA3);
            aB0 = dot2p(wregB[4 * g + 0], hh.x, aB0);
            aB1 = dot2p(wregB[4 * g + 1], hh.y, aB1);
            aB2 = dot2p(wregB[4 * g + 2], hh.z, aB2);
            aB3 = dot2p(wregB[4 * g + 3], hh.w, aB3);
        }
        // LDS section: pairs [136,192), hq groups [34,48).
#pragma unroll
        for (int g = P_REG / 4; g < (P_REG + P_LDS) / 4; ++g) {
            uint4 hh = hq4[g];
            int g2 = 2 * (g - P_REG / 4);
            uint4 wv0 = wlds[(g2 + 0) * 256 + t];
            uint4 wv1 = wlds[(g2 + 1) * 256 + t];
            aA0 = dot2p(wv0.x, hh.x, aA0);
            aA1 = dot2p(wv0.y, hh.y, aA1);
            aB0 = dot2p(wv0.z, hh.x, aB0);
            aB1 = dot2p(wv0.w, hh.y, aB1);
            aA2 = dot2p(wv1.x, hh.z, aA2);
            aA3 = dot2p(wv1.y, hh.w, aA3);
            aB2 = dot2p(wv1.z, hh.z, aB2);
            aB3 = dot2p(wv1.w, hh.w, aB3);
        }
        // Streamed section: pairs [192,256), hq groups [48,64).
#pragma unroll
        for (int k = 0; k < 16; ++k) {
            uint4 hh = hq4[(P_REG + P_LDS) / 4 + k];
            aA0 = dot2p(swA[k].x, hh.x, aA0);
            aA1 = dot2p(swA[k].y, hh.y, aA1);
            aA2 = dot2p(swA[k].z, hh.z, aA2);
            aA3 = dot2p(swA[k].w, hh.w, aA3);
            aB0 = dot2p(swB[k].x, hh.x, aB0);
            aB1 = dot2p(swB[k].y, hh.y, aB1);
            aB2 = dot2p(swB[k].z, hh.z, aB2);
            aB3 = dot2p(swB[k].w, hh.w, aB3);
        }

        float vA = fast_tanh(((aA0 + aA1) + (aA2 + aA3)) + xpv.x);
        float vB = fast_tanh(((aB0 + aB1) + (aB2 + aB3)) + xpv.y);
        float2 out2 = {vA, vB};
        *(float2*)(col + (size_t)s * BH) = out2;               // hidden_seq (fp32)
        unsigned int pk =
            (unsigned int)__builtin_bit_cast(unsigned short, (_Float16)vA) |
            ((unsigned int)__builtin_bit_cast(unsigned short, (_Float16)vB) << 16);
        h2u[(s + 1) & 1][t] = pk;
        // Relaxed barrier: wait LDS only; global store/loads stay in flight.
        asm volatile("s_waitcnt lgkmcnt(0)" ::: "memory");
        asm volatile("s_barrier" ::: "memory");
    }
}

// scores: sc_g[b][s] = dot(hbuf[s][b][:], hbuf[S-1][b][:]). Grid (64, 8), 256 thr.
__global__ __launch_bounds__(256) void attn_sc(const float* __restrict__ hbuf,
                                               float* __restrict__ sc_g) {
    const int b     = blockIdx.x;
    const int chunk = blockIdx.y;
    const int tid   = threadIdx.x;
    const int lane  = tid & 63;
    const int wv    = tid >> 6;
    __shared__ float fh[HID];
    fh[tid] = hbuf[(size_t)(S_LEN - 1) * BH + (size_t)b * HID + tid];
    fh[tid + 256] = hbuf[(size_t)(S_LEN - 1) * BH + (size_t)b * HID + tid + 256];
    __syncthreads();
    float4 f0 = *(const float4*)&fh[lane * 8];
    float4 f1 = *(const float4*)&fh[lane * 8 + 4];
    for (int i = 0; i < 32; ++i) {
        int s = chunk * 128 + wv * 32 + i;
        const float* hr = hbuf + (size_t)s * BH + (size_t)b * HID + lane * 8;
        float4 a0 = *(const float4*)hr;
        float4 a1 = *(const float4*)(hr + 4);
        float p = a0.x * f0.x + a0.y * f0.y + a0.z * f0.z + a0.w * f0.w +
                  a1.x * f1.x + a1.y * f1.y + a1.z * f1.z + a1.w * f1.w;
#pragma unroll
        for (int off = 32; off; off >>= 1) p += __shfl_down(p, off, 64);
        if (lane == 0) sc_g[(size_t)b * S_LEN + s] = p;
    }
}

// softmax (redundant per h-chunk) + context. Grid (64, 4), 256 thr, 128 h/WG.
__global__ __launch_bounds__(256) void attn_ctx(const float* __restrict__ hbuf,
                                                const float* __restrict__ sc_g,
                                                float* __restrict__ ctx_g) {
    const int b   = blockIdx.x;
    const int hc  = blockIdx.y * 128;
    const int tid = threadIdx.x;
    const int lane = tid & 63;
    const int wv   = tid >> 6;
    __shared__ float sc[S_LEN];
    __shared__ float red[4];
    __shared__ float part[256];
    for (int i = tid; i < S_LEN; i += 256) sc[i] = sc_g[(size_t)b * S_LEN + i];
    __syncthreads();
    float m = -1e30f;
    for (int i = tid; i < S_LEN; i += 256) m = fmaxf(m, sc[i]);
#pragma unroll
    for (int off = 32; off; off >>= 1) m = fmaxf(m, __shfl_down(m, off, 64));
    if (lane == 0) red[wv] = m;
    __syncthreads();
    m = fmaxf(fmaxf(red[0], red[1]), fmaxf(red[2], red[3]));
    float sum = 0.f;
    for (int i = tid; i < S_LEN; i += 256) {
        float e = __expf(sc[i] - m);
        sc[i] = e;
        sum += e;
    }
#pragma unroll
    for (int off = 32; off; off >>= 1) sum += __shfl_down(sum, off, 64);
    __syncthreads();
    if (lane == 0) red[wv] = sum;
    __syncthreads();
    float inv = 1.f / (red[0] + red[1] + red[2] + red[3]);
    const int h  = hc + (tid & 127);
    const int sh = tid >> 7;
    const float* hp = hbuf + (size_t)sh * 512 * BH + (size_t)b * HID + h;
    float c = 0.f;
#pragma unroll 4
    for (int s2 = 0; s2 < 512; ++s2)
        c += sc[sh * 512 + s2] * hp[(size_t)s2 * BH];
    part[tid] = c;
    __syncthreads();
    if (tid < 128) ctx_g[(size_t)b * HID + hc + tid] = (part[tid] + part[tid + 128]) * inv;
}

// out[b][o] = b_ho[o] + dot(ctx_g[b][:], W_ho[o][:]). Grid 64, 256 thr.
__global__ __launch_bounds__(256) void attn_fin(const float* __restrict__ ctx_g,
                                                const float* __restrict__ W_ho,
                                                const float* __restrict__ b_ho,
                                                float* __restrict__ out) {
    const int b   = blockIdx.x;
    const int tid = threadIdx.x;
    __shared__ float ctx[HID];
    ctx[tid] = ctx_g[(size_t)b * HID + tid];
    ctx[tid + 256] = ctx_g[(size_t)b * HID + tid + 256];
    __syncthreads();
    float o = b_ho[tid];
    const float* wr = W_ho + (size_t)tid * HID;
#pragma unroll 4
    for (int k = 0; k < HID; ++k) o += wr[k] * ctx[k];
    out[(size_t)b * OUT_SZ + tid] = o;
}

extern "C" void kernel_launch(void* const* d_in, const int* in_sizes, int n_in,
                              void* d_out, int out_size, void* d_ws, size_t ws_size,
                              hipStream_t stream) {
    const float* x    = (const float*)d_in[0];
    const float* W_ih = (const float*)d_in[1];
    const float* b_ih = (const float*)d_in[2];
    const float* W_ho = (const float*)d_in[3];
    const float* b_ho = (const float*)d_in[4];
    float* out = (float*)d_out;
    float* ws  = (float*)d_ws;

    float* xp = ws;
    unsigned int* wbase    = (unsigned int*)(ws + XP_FLOATS);
    unsigned int* wstr2    = wbase;                        // 32768 words (8192 uint4)
    unsigned int* wregbuf2 = wbase + 32768;                // 69632 words
    unsigned int* wldsbuf2 = wbase + 102400;               // 28672 words -> 131072
    uint4*        wpk      = (uint4*)(wbase + 131072);     // 16384 uint4 (256 KB)
    float*        sc_g     = (float*)wbase;                // overlay, post-rnn
    float*        ctx_g    = (float*)(wbase + 65536);      // overlay, post-rnn

    pack_w<<<dim3(512), dim3(256), 0, stream>>>(W_ih, wstr2, wregbuf2, wldsbuf2);
    pack_wf16<<<dim3(64), dim3(256), 0, stream>>>(W_ih, wpk);
    xproj_mfma<<<dim3(1024, 2), dim3(256), 0, stream>>>(x, wpk, b_ih, xp);
    rnn_f16<<<dim3(64), dim3(256), 0, stream>>>(wregbuf2, (const uint4*)wldsbuf2,
                                                (const uint4*)wstr2, xp);
    attn_sc<<<dim3(64, 8), dim3(256), 0, stream>>>(xp, sc_g);
    attn_ctx<<<dim3(64, 4), dim3(256), 0, stream>>>(xp, sc_g, ctx_g);
    attn_fin<<<dim3(64), dim3(256), 0, stream>>>(ctx_g, W_ho, b_ho, out);
}

// Round 6
// 2654.312 us; speedup vs baseline: 1.4420x; 1.4420x over previous
//
#include <hip/hip_runtime.h>
#include <cstdint>
#include <cmath>

#define S_LEN 1024
#define BATCH 64
#define IN_SZ 256
#define HID 512
#define OUT_SZ 256
#define WIH_LD 768  // W_ih leading dim = IN_SZ + HID
#define BH (BATCH * HID)            // 32768
#define XP_FLOATS (S_LEN * BH)      // 33,554,432 floats (128 MB)

// R6 recurrence: 1024 thr/WG (16 waves, 4/SIMD -> 128 unified regs/thread).
// Thread t: j = t>>1, k-half = t&1 (128 pairs). Partner lanes adjacent ->
// partials combine via one __shfl_xor(1); no extra barrier.
//
// Why (R5 post-mortem): plain VALU cannot source AGPRs; any live set beyond
// the 128 arch VGPRs pays one v_accvgpr_read per weight per step (~130
// insts/thread in R2/R4 = ~520 cyc/SIMD-step of pure tax; ~900 insts in R5).
// R6 is DESIGNED to fit 128: 64 reg-pairs + 8 sw uint4 (32 w) + ~26
// transients ~= 122. k-split also halves per-SIMD dot2 work (VALU ~1200 cyc)
// while per-CU hq broadcast stays at its 512-inst floor.
//
// Per-thread local pair q in [0,128), global p = (t&1)*128 + q, group g=q>>2:
//   g in [0,16)  -> register-resident (64 pairs)
//   g in [16,24) -> LDS, [g][t] uint4 tile, 16B lane stride (R5-validated,
//                   zero conflicts measured)
//   g in [24,32) -> streamed/step from L2, [t][8] uint4 contiguous (one base
//                   + imm offsets), single upfront batch (R1 lesson)
// hq reads: even/odd lanes read 2 distinct addresses per b128 (byte 16g vs
// 512+16g) -> same banks, 2-way aliasing = free (m136).

// ws word layout after xp (wbase = ws + XP_FLOATS):
//  [0, 32768)          wstr3     ([t][8] uint4; dead after rnn)
//  [32768, 98304)      wregbuf3  (64*1024 words [q][t]; dead after rnn)
//  [98304, 131072)     wldsbuf3  (8*1024 uint4 LDS image; dead after rnn)
//  [131072, 196608)    wpk       (xproj B-fragments, 16384 uint4 = 256 KB)
//  overlays (used only after rnn completes):
//  [0, 65536)          sc_g[64][1024]
//  [65536, 98304)      ctx_g[64][512]

typedef _Float16 h2v __attribute__((ext_vector_type(2)));
typedef _Float16 f16x8 __attribute__((ext_vector_type(8)));
typedef float f32x4 __attribute__((ext_vector_type(4)));

__device__ __forceinline__ float dot2p(unsigned int a, unsigned int b, float c) {
#if __has_builtin(__builtin_amdgcn_fdot2)
    return __builtin_amdgcn_fdot2(__builtin_bit_cast(h2v, a),
                                  __builtin_bit_cast(h2v, b), c, false);
#else
    h2v av = __builtin_bit_cast(h2v, a);
    h2v bv = __builtin_bit_cast(h2v, b);
    return c + (float)av.x * (float)bv.x + (float)av.y * (float)bv.y;
#endif
}

// Branch-free tanh: 1 - 2/(e^{2x}+1). ~1e-6 abs err, exact limits. (R2 win.)
__device__ __forceinline__ float fast_tanh(float x) {
    float e = __expf(2.0f * x);
#if __has_builtin(__builtin_amdgcn_rcpf)
    float r = __builtin_amdgcn_rcpf(e + 1.0f);
#else
    float r = 1.0f / (e + 1.0f);
#endif
    return __builtin_fmaf(-2.0f, r, 1.0f);
}

__global__ __launch_bounds__(256) void pack_w(const float* __restrict__ W_ih,
                                              unsigned int* __restrict__ wstr3,
                                              unsigned int* __restrict__ wregbuf3,
                                              unsigned int* __restrict__ wldsbuf3) {
    int idx = blockIdx.x * 256 + threadIdx.x;   // 0..131071
    int p = idx & 255;
    int j = idx >> 8;
    const float* src = W_ih + (size_t)j * WIH_LD + IN_SZ + 2 * p;
    unsigned short lo = __builtin_bit_cast(unsigned short, (_Float16)src[0]);
    unsigned short hi = __builtin_bit_cast(unsigned short, (_Float16)src[1]);
    unsigned int u = (unsigned int)lo | ((unsigned int)hi << 16);
    int t = 2 * j + (p >> 7);   // owning thread (j = t>>1, half = t&1)
    int q = p & 127;            // local pair index within the thread's half
    int g = q >> 2;
    int c = q & 3;
    if (g < 16) {
        wregbuf3[q * 1024 + t] = u;
    } else if (g < 24) {
        wldsbuf3[((g - 16) * 1024 + t) * 4 + c] = u;
    } else {
        wstr3[t * 32 + (g - 24) * 4 + c] = u;   // [t][8] uint4 contiguous
    }
}

// Pack Wx (W_ih[:, 0:256]) into MFMA B-fragment layout, f16.
__global__ __launch_bounds__(256) void pack_wf16(const float* __restrict__ W_ih,
                                                 uint4* __restrict__ wpk) {
    int idx = blockIdx.x * 256 + threadIdx.x;   // 0..16383
    if (idx >= 16384) return;
    int nt   = idx >> 9;
    int ks   = (idx >> 6) & 7;
    int lane = idx & 63;
    int n  = nt * 16 + (lane & 15);
    int kb = ks * 32 + (lane >> 4) * 8;
    const float* src = W_ih + (size_t)n * WIH_LD + kb;
    union { uint4 u; _Float16 h[8]; } v;
#pragma unroll
    for (int i = 0; i < 8; ++i) v.h[i] = (_Float16)src[i];
    wpk[idx] = v.u;
}

// xp[s][b][h] = dot(x[b][s][:], Wx[h][:]) + b_ih[h], via f16 MFMA (fp32 accum).
#define AH_LD 264   // 256 + 8-half pad
__global__ __launch_bounds__(256) void xproj_mfma(const float* __restrict__ x,
                                                  const uint4* __restrict__ wpk,
                                                  const float* __restrict__ b_ih,
                                                  float* __restrict__ xp) {
    const int s    = blockIdx.x;
    const int half = blockIdx.y;
    const int tid  = threadIdx.x;
    __shared__ __align__(16) _Float16 Ah[32 * AH_LD];
    __shared__ float bsh[HID];
    bsh[tid] = b_ih[tid];
    bsh[tid + 256] = b_ih[tid + 256];
    {
        int r  = tid >> 3;
        int c0 = (tid & 7) * 32;
        const float4* s4 = (const float4*)(x + ((size_t)(half * 32 + r) * S_LEN + s) * IN_SZ + c0);
        _Float16* dst = &Ah[r * AH_LD + c0];
#pragma unroll
        for (int i = 0; i < 8; ++i) {
            float4 v = s4[i];
            dst[4 * i + 0] = (_Float16)v.x;
            dst[4 * i + 1] = (_Float16)v.y;
            dst[4 * i + 2] = (_Float16)v.z;
            dst[4 * i + 3] = (_Float16)v.w;
        }
    }
    __syncthreads();
    const int lane = tid & 63;
    const int w    = tid >> 6;
    const int mt   = w & 1;
    const int ntb  = (w >> 1) * 16;
    f16x8 areg[8];
#pragma unroll
    for (int ks = 0; ks < 8; ++ks)
        areg[ks] = *(const f16x8*)&Ah[(mt * 16 + (lane & 15)) * AH_LD + ks * 32 + (lane >> 4) * 8];
    const int brow  = half * 32 + mt * 16 + (lane >> 4) * 4;
    const int ncol0 = lane & 15;
    for (int nt2 = 0; nt2 < 16; ++nt2) {
        int nt = ntb + nt2;
        const uint4* bp = wpk + (size_t)nt * 8 * 64 + lane;
        f32x4 acc = {0.f, 0.f, 0.f, 0.f};
#pragma unroll
        for (int ks = 0; ks < 8; ++ks) {
            uint4 bu = bp[ks * 64];
            acc = __builtin_amdgcn_mfma_f32_16x16x32_f16(
                areg[ks], __builtin_bit_cast(f16x8, bu), acc, 0, 0, 0);
        }
        int n = nt * 16 + ncol0;
        float bias = bsh[n];
        float* outp = xp + (size_t)s * BH + (size_t)brow * HID + n;
#pragma unroll
        for (int r = 0; r < 4; ++r) outp[(size_t)r * HID] = acc[r] + bias;
    }
}

// Recurrence: one WG (1024 thr, 16 waves, 4/SIMD) per batch; in-wave k-split.
__global__ __launch_bounds__(1024, 4) void rnn_f16(const unsigned int* __restrict__ wregbuf3,
                                                   const uint4* __restrict__ wldsbuf3,
                                                   const uint4* __restrict__ wstr3,
                                                   float* __restrict__ xp) {
    const int b = blockIdx.x;
    const int t = threadIdx.x;            // 0..1023
    const int j = t >> 1;                 // output index 0..511
    const int half = t & 1;               // k-half

    __shared__ __align__(16) uint4 wlds4[8 * 1024];          // 131,072 B weights
    __shared__ __align__(16) unsigned short h16[2][512];     // 2 KB f16 state

    unsigned int wreg[64];
#pragma unroll
    for (int q = 0; q < 64; ++q) wreg[q] = wregbuf3[q * 1024 + t];

    // Stage LDS weight image (coalesced uint4 linear copy).
    for (int i = t; i < 8 * 1024; i += 1024) wlds4[i] = wldsbuf3[i];
    if (t < 512) h16[0][t] = 0;   // f16 +0.0
    __syncthreads();

    const uint4* swp = wstr3 + (size_t)t * 8;   // contiguous, imm-offset loads
    float* col = xp + (size_t)b * HID + j;

    for (int s = 0; s < S_LEN; ++s) {
        const uint4* hq4 = (const uint4*)&h16[s & 1][0];   // 64 uint4 = 256 pairs
        const int hb = half * 32;                           // this half's groups

        float xpv = 0.f;
        if (half == 0) xpv = col[(size_t)s * BH];

        // Streamed weights: single upfront batch (8 dwordx4, L2-resident).
        uint4 sw[8];
#pragma unroll
        for (int g = 0; g < 8; ++g) sw[g] = swp[g];

        float a0 = 0.f, a1 = 0.f, a2 = 0.f, a3 = 0.f;
        // Register section: local groups [0,16).
#pragma unroll
        for (int g = 0; g < 16; ++g) {
            uint4 hh = hq4[hb + g];
            a0 = dot2p(wreg[4 * g + 0], hh.x, a0);
            a1 = dot2p(wreg[4 * g + 1], hh.y, a1);
            a2 = dot2p(wreg[4 * g + 2], hh.z, a2);
            a3 = dot2p(wreg[4 * g + 3], hh.w, a3);
        }
        // LDS section: local groups [16,24).
#pragma unroll
        for (int g = 0; g < 8; ++g) {
            uint4 wv = wlds4[g * 1024 + t];
            uint4 hh = hq4[hb + 16 + g];
            a0 = dot2p(wv.x, hh.x, a0);
            a1 = dot2p(wv.y, hh.y, a1);
            a2 = dot2p(wv.z, hh.z, a2);
            a3 = dot2p(wv.w, hh.w, a3);
        }
        // Streamed section: local groups [24,32).
#pragma unroll
        for (int g = 0; g < 8; ++g) {
            uint4 hh = hq4[hb + 24 + g];
            a0 = dot2p(sw[g].x, hh.x, a0);
            a1 = dot2p(sw[g].y, hh.y, a1);
            a2 = dot2p(sw[g].z, hh.z, a2);
            a3 = dot2p(sw[g].w, hh.w, a3);
        }

        float partial = (a0 + a1) + (a2 + a3);
        partial += __shfl_xor(partial, 1, 64);   // combine k-halves (adjacent lanes)

        if (half == 0) {
            float v = fast_tanh(partial + xpv);
            col[(size_t)s * BH] = v;                               // hidden_seq (fp32)
            h16[(s + 1) & 1][j] =
                __builtin_bit_cast(unsigned short, (_Float16)v);
        }
        // Relaxed barrier: wait LDS only; global store/loads stay in flight.
        asm volatile("s_waitcnt lgkmcnt(0)" ::: "memory");
        asm volatile("s_barrier" ::: "memory");
    }
}

// scores: sc_g[b][s] = dot(hbuf[s][b][:], hbuf[S-1][b][:]). Grid (64, 8), 256 thr.
__global__ __launch_bounds__(256) void attn_sc(const float* __restrict__ hbuf,
                                               float* __restrict__ sc_g) {
    const int b     = blockIdx.x;
    const int chunk = blockIdx.y;
    const int tid   = threadIdx.x;
    const int lane  = tid & 63;
    const int wv    = tid >> 6;
    __shared__ float fh[HID];
    fh[tid] = hbuf[(size_t)(S_LEN - 1) * BH + (size_t)b * HID + tid];
    fh[tid + 256] = hbuf[(size_t)(S_LEN - 1) * BH + (size_t)b * HID + tid + 256];
    __syncthreads();
    float4 f0 = *(const float4*)&fh[lane * 8];
    float4 f1 = *(const float4*)&fh[lane * 8 + 4];
    for (int i = 0; i < 32; ++i) {
        int s = chunk * 128 + wv * 32 + i;
        const float* hr = hbuf + (size_t)s * BH + (size_t)b * HID + lane * 8;
        float4 a0 = *(const float4*)hr;
        float4 a1 = *(const float4*)(hr + 4);
        float p = a0.x * f0.x + a0.y * f0.y + a0.z * f0.z + a0.w * f0.w +
                  a1.x * f1.x + a1.y * f1.y + a1.z * f1.z + a1.w * f1.w;
#pragma unroll
        for (int off = 32; off; off >>= 1) p += __shfl_down(p, off, 64);
        if (lane == 0) sc_g[(size_t)b * S_LEN + s] = p;
    }
}

// softmax (redundant per h-chunk) + context. Grid (64, 4), 256 thr, 128 h/WG.
__global__ __launch_bounds__(256) void attn_ctx(const float* __restrict__ hbuf,
                                                const float* __restrict__ sc_g,
                                                float* __restrict__ ctx_g) {
    const int b   = blockIdx.x;
    const int hc  = blockIdx.y * 128;
    const int tid = threadIdx.x;
    const int lane = tid & 63;
    const int wv   = tid >> 6;
    __shared__ float sc[S_LEN];
    __shared__ float red[4];
    __shared__ float part[256];
    for (int i = tid; i < S_LEN; i += 256) sc[i] = sc_g[(size_t)b * S_LEN + i];
    __syncthreads();
    float m = -1e30f;
    for (int i = tid; i < S_LEN; i += 256) m = fmaxf(m, sc[i]);
#pragma unroll
    for (int off = 32; off; off >>= 1) m = fmaxf(m, __shfl_down(m, off, 64));
    if (lane == 0) red[wv] = m;
    __syncthreads();
    m = fmaxf(fmaxf(red[0], red[1]), fmaxf(red[2], red[3]));
    float sum = 0.f;
    for (int i = tid; i < S_LEN; i += 256) {
        float e = __expf(sc[i] - m);
        sc[i] = e;
        sum += e;
    }
#pragma unroll
    for (int off = 32; off; off >>= 1) sum += __shfl_down(sum, off, 64);
    __syncthreads();
    if (lane == 0) red[wv] = sum;
    __syncthreads();
    float inv = 1.f / (red[0] + red[1] + red[2] + red[3]);
    const int h  = hc + (tid & 127);
    const int sh = tid >> 7;
    const float* hp = hbuf + (size_t)sh * 512 * BH + (size_t)b * HID + h;
    float c = 0.f;
#pragma unroll 4
    for (int s2 = 0; s2 < 512; ++s2)
        c += sc[sh * 512 + s2] * hp[(size_t)s2 * BH];
    part[tid] = c;
    __syncthreads();
    if (tid < 128) ctx_g[(size_t)b * HID + hc + tid] = (part[tid] + part[tid + 128]) * inv;
}

// out[b][o] = b_ho[o] + dot(ctx_g[b][:], W_ho[o][:]). Grid 64, 256 thr.
__global__ __launch_bounds__(256) void attn_fin(const float* __restrict__ ctx_g,
                                                const float* __restrict__ W_ho,
                                                const float* __restrict__ b_ho,
                                                float* __restrict__ out) {
    const int b   = blockIdx.x;
    const int tid = threadIdx.x;
    __shared__ float ctx[HID];
    ctx[tid] = ctx_g[(size_t)b * HID + tid];
    ctx[tid + 256] = ctx_g[(size_t)b * HID + tid + 256];
    __syncthreads();
    float o = b_ho[tid];
    const float* wr = W_ho + (size_t)tid * HID;
#pragma unroll 4
    for (int k = 0; k < HID; ++k) o += wr[k] * ctx[k];
    out[(size_t)b * OUT_SZ + tid] = o;
}

extern "C" void kernel_launch(void* const* d_in, const int* in_sizes, int n_in,
                              void* d_out, int out_size, void* d_ws, size_t ws_size,
                              hipStream_t stream) {
    const float* x    = (const float*)d_in[0];
    const float* W_ih = (const float*)d_in[1];
    const float* b_ih = (const float*)d_in[2];
    const float* W_ho = (const float*)d_in[3];
    const float* b_ho = (const float*)d_in[4];
    float* out = (float*)d_out;
    float* ws  = (float*)d_ws;

    float* xp = ws;
    unsigned int* wbase    = (unsigned int*)(ws + XP_FLOATS);
    unsigned int* wstr3    = wbase;                        // 32768 words (8192 uint4)
    unsigned int* wregbuf3 = wbase + 32768;                // 65536 words
    unsigned int* wldsbuf3 = wbase + 98304;                // 32768 words -> 131072
    uint4*        wpk      = (uint4*)(wbase + 131072);     // 16384 uint4 (256 KB)
    float*        sc_g     = (float*)wbase;                // overlay, post-rnn
    float*        ctx_g    = (float*)(wbase + 65536);      // overlay, post-rnn

    pack_w<<<dim3(512), dim3(256), 0, stream>>>(W_ih, wstr3, wregbuf3, wldsbuf3);
    pack_wf16<<<dim3(64), dim3(256), 0, stream>>>(W_ih, wpk);
    xproj_mfma<<<dim3(1024, 2), dim3(256), 0, stream>>>(x, wpk, b_ih, xp);
    rnn_f16<<<dim3(64), dim3(1024), 0, stream>>>(wregbuf3, (const uint4*)wldsbuf3,
                                                 (const uint4*)wstr3, xp);
    attn_sc<<<dim3(64, 8), dim3(256), 0, stream>>>(xp, sc_g);
    attn_ctx<<<dim3(64, 4), dim3(256), 0, stream>>>(xp, sc_g, ctx_g);
    attn_fin<<<dim3(64), dim3(256), 0, stream>>>(ctx_g, W_ho, b_ho, out);
}

// Round 7
// 2375.229 us; speedup vs baseline: 1.6114x; 1.1175x over previous
//
#include <hip/hip_runtime.h>
#include <cstdint>
#include <cmath>

#define S_LEN 1024
#define BATCH 64
#define IN_SZ 256
#define HID 512
#define OUT_SZ 256
#define WIH_LD 768  // W_ih leading dim = IN_SZ + HID
#define BH (BATCH * HID)            // 32768
#define XP_FLOATS (S_LEN * BH)      // 33,554,432 floats (128 MB)

// R7 recurrence: 512 thr/WG, 8 waves (2/SIMD — R4's validated occupancy).
// WAVE-level k-split: waves 0-3 own k-half 0 (pairs [0,128)), waves 4-7 own
// k-half 1 (pairs [128,256)). Thread (H, u): outputs j0=2u, j1=2u+1.
//  - hq reads are WAVE-UNIFORM (byte (H*32+g)*16): true broadcast, zero bank
//    conflicts by construction. Per-CU-step hq issue: 256 (R4: 512; R6's
//    lane-level split: 512 + 1.3e8 conflicts — measured, now avoided).
//  - Weight volumes per thread IDENTICAL to R4's validated mix:
//      g in [0,22)  -> 44 uint4 register-resident (176 words)
//      g in [22,25) -> LDS [H][gl][jj][u] uint4, 16B lane stride (R5-validated
//                      conflict-free pattern), 6 b128/thread/step (24 words)
//      g in [25,32) -> streamed from L2, CONTIGUOUS [t][14] uint4 (one base +
//                      imm offsets; R6-validated, no over-fetch), single
//                      upfront batch (R1 lesson), 56 words
//  - Cross-half combine: half-1 writes float2 partials to 2KB LDS scratch,
//    barrier, half-0 adds + tanh + stores. 2 barriers/step total.
#define GR 22
#define GL 3
#define GS 7

// ws word layout after xp (wbase = ws + XP_FLOATS):
//  [0, 28672)          wstr      ([t][14] uint4; dead after rnn)
//  [28672, 118784)     wregbuf   (22528 uint4 [H][g][jj][u]; dead after rnn)
//  [118784, 131072)    wldsbuf   (3072 uint4 LDS image; dead after rnn)
//  [131072, 196608)    wpk       (xproj B-fragments, 16384 uint4 = 256 KB)
//  overlays (used only after rnn completes):
//  [0, 65536)          sc_g[64][1024]
//  [65536, 98304)      ctx_g[64][512]

typedef _Float16 h2v __attribute__((ext_vector_type(2)));
typedef _Float16 f16x8 __attribute__((ext_vector_type(8)));
typedef float f32x4 __attribute__((ext_vector_type(4)));

__device__ __forceinline__ float dot2p(unsigned int a, unsigned int b, float c) {
#if __has_builtin(__builtin_amdgcn_fdot2)
    return __builtin_amdgcn_fdot2(__builtin_bit_cast(h2v, a),
                                  __builtin_bit_cast(h2v, b), c, false);
#else
    h2v av = __builtin_bit_cast(h2v, a);
    h2v bv = __builtin_bit_cast(h2v, b);
    return c + (float)av.x * (float)bv.x + (float)av.y * (float)bv.y;
#endif
}

// Branch-free tanh: 1 - 2/(e^{2x}+1). ~1e-6 abs err, exact limits. (R2 win.)
__device__ __forceinline__ float fast_tanh(float x) {
    float e = __expf(2.0f * x);
#if __has_builtin(__builtin_amdgcn_rcpf)
    float r = __builtin_amdgcn_rcpf(e + 1.0f);
#else
    float r = 1.0f / (e + 1.0f);
#endif
    return __builtin_fmaf(-2.0f, r, 1.0f);
}

__global__ __launch_bounds__(256) void pack_w(const float* __restrict__ W_ih,
                                              unsigned int* __restrict__ wstr,
                                              unsigned int* __restrict__ wregbuf,
                                              unsigned int* __restrict__ wldsbuf) {
    int idx = blockIdx.x * 256 + threadIdx.x;   // 0..131071
    int p = idx & 255;
    int j = idx >> 8;
    const float* src = W_ih + (size_t)j * WIH_LD + IN_SZ + 2 * p;
    unsigned short lo = __builtin_bit_cast(unsigned short, (_Float16)src[0]);
    unsigned short hi = __builtin_bit_cast(unsigned short, (_Float16)src[1]);
    unsigned int u32 = (unsigned int)lo | ((unsigned int)hi << 16);
    int H  = p >> 7;          // k-half
    int q  = p & 127;
    int g  = q >> 2;          // pair-group 0..31
    int c  = q & 3;
    int u  = j >> 1;          // thread-in-half
    int jj = j & 1;           // which of the thread's two outputs
    if (g < GR) {
        wregbuf[(((H * GR + g) * 2 + jj) * 256 + u) * 4 + c] = u32;
    } else if (g < GR + GL) {
        int gl = g - GR;
        wldsbuf[(((H * GL + gl) * 2 + jj) * 256 + u) * 4 + c] = u32;
    } else {
        int gs = g - (GR + GL);
        int t  = H * 256 + u;
        wstr[((t * GS + gs) * 2 + jj) * 4 + c] = u32;   // contiguous per thread
    }
}

// Pack Wx (W_ih[:, 0:256]) into MFMA B-fragment layout, f16.
__global__ __launch_bounds__(256) void pack_wf16(const float* __restrict__ W_ih,
                                                 uint4* __restrict__ wpk) {
    int idx = blockIdx.x * 256 + threadIdx.x;   // 0..16383
    if (idx >= 16384) return;
    int nt   = idx >> 9;
    int ks   = (idx >> 6) & 7;
    int lane = idx & 63;
    int n  = nt * 16 + (lane & 15);
    int kb = ks * 32 + (lane >> 4) * 8;
    const float* src = W_ih + (size_t)n * WIH_LD + kb;
    union { uint4 u; _Float16 h[8]; } v;
#pragma unroll
    for (int i = 0; i < 8; ++i) v.h[i] = (_Float16)src[i];
    wpk[idx] = v.u;
}

// xp[s][b][h] = dot(x[b][s][:], Wx[h][:]) + b_ih[h], via f16 MFMA (fp32 accum).
#define AH_LD 264   // 256 + 8-half pad
__global__ __launch_bounds__(256) void xproj_mfma(const float* __restrict__ x,
                                                  const uint4* __restrict__ wpk,
                                                  const float* __restrict__ b_ih,
                                                  float* __restrict__ xp) {
    const int s    = blockIdx.x;
    const int half = blockIdx.y;
    const int tid  = threadIdx.x;
    __shared__ __align__(16) _Float16 Ah[32 * AH_LD];
    __shared__ float bsh[HID];
    bsh[tid] = b_ih[tid];
    bsh[tid + 256] = b_ih[tid + 256];
    {
        int r  = tid >> 3;
        int c0 = (tid & 7) * 32;
        const float4* s4 = (const float4*)(x + ((size_t)(half * 32 + r) * S_LEN + s) * IN_SZ + c0);
        _Float16* dst = &Ah[r * AH_LD + c0];
#pragma unroll
        for (int i = 0; i < 8; ++i) {
            float4 v = s4[i];
            dst[4 * i + 0] = (_Float16)v.x;
            dst[4 * i + 1] = (_Float16)v.y;
            dst[4 * i + 2] = (_Float16)v.z;
            dst[4 * i + 3] = (_Float16)v.w;
        }
    }
    __syncthreads();
    const int lane = tid & 63;
    const int w    = tid >> 6;
    const int mt   = w & 1;
    const int ntb  = (w >> 1) * 16;
    f16x8 areg[8];
#pragma unroll
    for (int ks = 0; ks < 8; ++ks)
        areg[ks] = *(const f16x8*)&Ah[(mt * 16 + (lane & 15)) * AH_LD + ks * 32 + (lane >> 4) * 8];
    const int brow  = half * 32 + mt * 16 + (lane >> 4) * 4;
    const int ncol0 = lane & 15;
    for (int nt2 = 0; nt2 < 16; ++nt2) {
        int nt = ntb + nt2;
        const uint4* bp = wpk + (size_t)nt * 8 * 64 + lane;
        f32x4 acc = {0.f, 0.f, 0.f, 0.f};
#pragma unroll
        for (int ks = 0; ks < 8; ++ks) {
            uint4 bu = bp[ks * 64];
            acc = __builtin_amdgcn_mfma_f32_16x16x32_f16(
                areg[ks], __builtin_bit_cast(f16x8, bu), acc, 0, 0, 0);
        }
        int n = nt * 16 + ncol0;
        float bias = bsh[n];
        float* outp = xp + (size_t)s * BH + (size_t)brow * HID + n;
#pragma unroll
        for (int r = 0; r < 4; ++r) outp[(size_t)r * HID] = acc[r] + bias;
    }
}

// Recurrence: one WG (512 thr, 8 waves, 2/SIMD) per batch; wave-level k-split,
// 2 outputs/thread.
__global__ __launch_bounds__(512, 2) void rnn_f16(const uint4* __restrict__ wregbuf,
                                                  const uint4* __restrict__ wldsbuf,
                                                  const uint4* __restrict__ wstr,
                                                  float* __restrict__ xp) {
    const int b = blockIdx.x;
    const int t = threadIdx.x;            // 0..511
    const int H = t >> 8;                 // k-half (wave-uniform: waves 0-3 / 4-7)
    const int u = t & 255;                // thread-in-half; outputs j0=2u, j1=2u+1

    __shared__ __align__(16) uint4 wlds[(GL * 2 * 2) * 256];   // 49,152 B
    __shared__ __align__(16) unsigned int h16[2][256];         // 2 x 1 KB packed f16
    __shared__ __align__(8)  float2 pscr[256];                 // 2 KB partial scratch

    // Register-resident weights: 44 uint4 = 176 words (R4-equal volume).
    uint4 wrA[GR], wrB[GR];
    {
        const uint4* wb = wregbuf + (size_t)H * (GR * 2 * 256) + u;
#pragma unroll
        for (int g = 0; g < GR; ++g) {
            wrA[g] = wb[(g * 2 + 0) * 256];
            wrB[g] = wb[(g * 2 + 1) * 256];
        }
    }
    for (int i = t; i < (GL * 2 * 2) * 256; i += 512) wlds[i] = wldsbuf[i];
    if (t < 256) h16[0][t] = 0;   // two f16 +0.0
    __syncthreads();

    const uint4* swp = wstr + (size_t)t * (GS * 2);            // 14 uint4, contiguous
    const uint4* wl  = wlds + (size_t)H * (GL * 2 * 256) + u;
    float* colx = xp + (size_t)b * HID + 2 * u;                // float2 slot (j0,j1)

    for (int s = 0; s < S_LEN; ++s) {
        const uint4* hq4 = (const uint4*)&h16[s & 1][0];       // 64 uint4 = 256 pairs
        const int hb = H * 32;                                  // this half's groups

        float2 xpv; xpv.x = 0.f; xpv.y = 0.f;
        if (H == 0) xpv = *(const float2*)(colx + (size_t)s * BH);

        // Streamed weights: single upfront batch, one base + imm offsets.
        uint4 sw[GS * 2];
#pragma unroll
        for (int i = 0; i < GS * 2; ++i) sw[i] = swp[i];

        float aA0 = 0.f, aA1 = 0.f, aA2 = 0.f, aA3 = 0.f;
        float aB0 = 0.f, aB1 = 0.f, aB2 = 0.f, aB3 = 0.f;

        // Register section: groups [0,22).
#pragma unroll
        for (int g = 0; g < GR; ++g) {
            uint4 hh = hq4[hb + g];
            aA0 = dot2p(wrA[g].x, hh.x, aA0);
            aA1 = dot2p(wrA[g].y, hh.y, aA1);
            aA2 = dot2p(wrA[g].z, hh.z, aA2);
            aA3 = dot2p(wrA[g].w, hh.w, aA3);
            aB0 = dot2p(wrB[g].x, hh.x, aB0);
            aB1 = dot2p(wrB[g].y, hh.y, aB1);
            aB2 = dot2p(wrB[g].z, hh.z, aB2);
            aB3 = dot2p(wrB[g].w, hh.w, aB3);
        }
        // LDS section: groups [22,25).
#pragma unroll
        for (int gl = 0; gl < GL; ++gl) {
            uint4 hh = hq4[hb + GR + gl];
            uint4 wA = wl[(gl * 2 + 0) * 256];
            uint4 wB = wl[(gl * 2 + 1) * 256];
            aA0 = dot2p(wA.x, hh.x, aA0);
            aA1 = dot2p(wA.y, hh.y, aA1);
            aA2 = dot2p(wA.z, hh.z, aA2);
            aA3 = dot2p(wA.w, hh.w, aA3);
            aB0 = dot2p(wB.x, hh.x, aB0);
            aB1 = dot2p(wB.y, hh.y, aB1);
            aB2 = dot2p(wB.z, hh.z, aB2);
            aB3 = dot2p(wB.w, hh.w, aB3);
        }
        // Streamed section: groups [25,32).
#pragma unroll
        for (int gs = 0; gs < GS; ++gs) {
            uint4 hh = hq4[hb + GR + GL + gs];
            uint4 wA = sw[gs * 2 + 0];
            uint4 wB = sw[gs * 2 + 1];
            aA0 = dot2p(wA.x, hh.x, aA0);
            aA1 = dot2p(wA.y, hh.y, aA1);
            aA2 = dot2p(wA.z, hh.z, aA2);
            aA3 = dot2p(wA.w, hh.w, aA3);
            aB0 = dot2p(wB.x, hh.x, aB0);
            aB1 = dot2p(wB.y, hh.y, aB1);
            aB2 = dot2p(wB.z, hh.z, aB2);
            aB3 = dot2p(wB.w, hh.w, aB3);
        }

        float pA = (aA0 + aA1) + (aA2 + aA3);
        float pB = (aB0 + aB1) + (aB2 + aB3);
        if (H == 1) { float2 pv; pv.x = pA; pv.y = pB; pscr[u] = pv; }
        asm volatile("s_waitcnt lgkmcnt(0)" ::: "memory");
        asm volatile("s_barrier" ::: "memory");
        if (H == 0) {
            float2 pr = pscr[u];
            float vA = fast_tanh(pA + pr.x + xpv.x);
            float vB = fast_tanh(pB + pr.y + xpv.y);
            float2 v2; v2.x = vA; v2.y = vB;
            *(float2*)(colx + (size_t)s * BH) = v2;            // hidden_seq (fp32)
            unsigned int pk =
                (unsigned int)__builtin_bit_cast(unsigned short, (_Float16)vA) |
                ((unsigned int)__builtin_bit_cast(unsigned short, (_Float16)vB) << 16);
            h16[(s + 1) & 1][u] = pk;
        }
        // Relaxed barrier: wait LDS only; global store/loads stay in flight.
        asm volatile("s_waitcnt lgkmcnt(0)" ::: "memory");
        asm volatile("s_barrier" ::: "memory");
    }
}

// scores: sc_g[b][s] = dot(hbuf[s][b][:], hbuf[S-1][b][:]). Grid (64, 8), 256 thr.
__global__ __launch_bounds__(256) void attn_sc(const float* __restrict__ hbuf,
                                               float* __restrict__ sc_g) {
    const int b     = blockIdx.x;
    const int chunk = blockIdx.y;
    const int tid   = threadIdx.x;
    const int lane  = tid & 63;
    const int wv    = tid >> 6;
    __shared__ float fh[HID];
    fh[tid] = hbuf[(size_t)(S_LEN - 1) * BH + (size_t)b * HID + tid];
    fh[tid + 256] = hbuf[(size_t)(S_LEN - 1) * BH + (size_t)b * HID + tid + 256];
    __syncthreads();
    float4 f0 = *(const float4*)&fh[lane * 8];
    float4 f1 = *(const float4*)&fh[lane * 8 + 4];
    for (int i = 0; i < 32; ++i) {
        int s = chunk * 128 + wv * 32 + i;
        const float* hr = hbuf + (size_t)s * BH + (size_t)b * HID + lane * 8;
        float4 a0 = *(const float4*)hr;
        float4 a1 = *(const float4*)(hr + 4);
        float p = a0.x * f0.x + a0.y * f0.y + a0.z * f0.z + a0.w * f0.w +
                  a1.x * f1.x + a1.y * f1.y + a1.z * f1.z + a1.w * f1.w;
#pragma unroll
        for (int off = 32; off; off >>= 1) p += __shfl_down(p, off, 64);
        if (lane == 0) sc_g[(size_t)b * S_LEN + s] = p;
    }
}

// softmax (redundant per h-chunk) + context. Grid (64, 4), 256 thr, 128 h/WG.
__global__ __launch_bounds__(256) void attn_ctx(const float* __restrict__ hbuf,
                                                const float* __restrict__ sc_g,
                                                float* __restrict__ ctx_g) {
    const int b   = blockIdx.x;
    const int hc  = blockIdx.y * 128;
    const int tid = threadIdx.x;
    const int lane = tid & 63;
    const int wv   = tid >> 6;
    __shared__ float sc[S_LEN];
    __shared__ float red[4];
    __shared__ float part[256];
    for (int i = tid; i < S_LEN; i += 256) sc[i] = sc_g[(size_t)b * S_LEN + i];
    __syncthreads();
    float m = -1e30f;
    for (int i = tid; i < S_LEN; i += 256) m = fmaxf(m, sc[i]);
#pragma unroll
    for (int off = 32; off; off >>= 1) m = fmaxf(m, __shfl_down(m, off, 64));
    if (lane == 0) red[wv] = m;
    __syncthreads();
    m = fmaxf(fmaxf(red[0], red[1]), fmaxf(red[2], red[3]));
    float sum = 0.f;
    for (int i = tid; i < S_LEN; i += 256) {
        float e = __expf(sc[i] - m);
        sc[i] = e;
        sum += e;
    }
#pragma unroll
    for (int off = 32; off; off >>= 1) sum += __shfl_down(sum, off, 64);
    __syncthreads();
    if (lane == 0) red[wv] = sum;
    __syncthreads();
    float inv = 1.f / (red[0] + red[1] + red[2] + red[3]);
    const int h  = hc + (tid & 127);
    const int sh = tid >> 7;
    const float* hp = hbuf + (size_t)sh * 512 * BH + (size_t)b * HID + h;
    float c = 0.f;
#pragma unroll 4
    for (int s2 = 0; s2 < 512; ++s2)
        c += sc[sh * 512 + s2] * hp[(size_t)s2 * BH];
    part[tid] = c;
    __syncthreads();
    if (tid < 128) ctx_g[(size_t)b * HID + hc + tid] = (part[tid] + part[tid + 128]) * inv;
}

// out[b][o] = b_ho[o] + dot(ctx_g[b][:], W_ho[o][:]). Grid 64, 256 thr.
__global__ __launch_bounds__(256) void attn_fin(const float* __restrict__ ctx_g,
                                                const float* __restrict__ W_ho,
                                                const float* __restrict__ b_ho,
                                                float* __restrict__ out) {
    const int b   = blockIdx.x;
    const int tid = threadIdx.x;
    __shared__ float ctx[HID];
    ctx[tid] = ctx_g[(size_t)b * HID + tid];
    ctx[tid + 256] = ctx_g[(size_t)b * HID + tid + 256];
    __syncthreads();
    float o = b_ho[tid];
    const float* wr = W_ho + (size_t)tid * HID;
#pragma unroll 4
    for (int k = 0; k < HID; ++k) o += wr[k] * ctx[k];
    out[(size_t)b * OUT_SZ + tid] = o;
}

extern "C" void kernel_launch(void* const* d_in, const int* in_sizes, int n_in,
                              void* d_out, int out_size, void* d_ws, size_t ws_size,
                              hipStream_t stream) {
    const float* x    = (const float*)d_in[0];
    const float* W_ih = (const float*)d_in[1];
    const float* b_ih = (const float*)d_in[2];
    const float* W_ho = (const float*)d_in[3];
    const float* b_ho = (const float*)d_in[4];
    float* out = (float*)d_out;
    float* ws  = (float*)d_ws;

    float* xp = ws;
    unsigned int* wbase   = (unsigned int*)(ws + XP_FLOATS);
    unsigned int* wstr    = wbase;                         // 28672 words (7168 uint4)
    unsigned int* wregbuf = wbase + 28672;                 // 90112 words (22528 uint4)
    unsigned int* wldsbuf = wbase + 118784;                // 12288 words (3072 uint4)
    uint4*        wpk     = (uint4*)(wbase + 131072);      // 16384 uint4 (256 KB)
    float*        sc_g    = (float*)wbase;                 // overlay, post-rnn
    float*        ctx_g   = (float*)(wbase + 65536);       // overlay, post-rnn

    pack_w<<<dim3(512), dim3(256), 0, stream>>>(W_ih, wstr, wregbuf, wldsbuf);
    pack_wf16<<<dim3(64), dim3(256), 0, stream>>>(W_ih, wpk);
    xproj_mfma<<<dim3(1024, 2), dim3(256), 0, stream>>>(x, wpk, b_ih, xp);
    rnn_f16<<<dim3(64), dim3(512), 0, stream>>>((const uint4*)wregbuf,
                                                (const uint4*)wldsbuf,
                                                (const uint4*)wstr, xp);
    attn_sc<<<dim3(64, 8), dim3(256), 0, stream>>>(xp, sc_g);
    attn_ctx<<<dim3(64, 4), dim3(256), 0, stream>>>(xp, sc_g, ctx_g);
    attn_fin<<<dim3(64), dim3(256), 0, stream>>>(ctx_g, W_ho, b_ho, out);
}